// Round 12
// baseline (676.070 us; speedup 1.0000x reference)
//
#include <hip/hip_runtime.h>
#include <hip/hip_bf16.h>

typedef short short8v __attribute__((ext_vector_type(8)));
typedef short short4v __attribute__((ext_vector_type(4)));
typedef float f32x4v __attribute__((ext_vector_type(4)));

#define T_LEN 512
#define BATCH 64
#define INDIM 1280
#define HDIM 128
#define G4 512      // 4*H (one direction)
#define NCOLS 1024  // both directions
#define NCLS 263

typedef __attribute__((address_space(1))) const void gvoid_t;
typedef __attribute__((address_space(3))) void lvoid_t;
#define GLOAD_LDS16(g, l) __builtin_amdgcn_global_load_lds((gvoid_t*)(g), (lvoid_t*)(l), 16, 0, 0)

static __device__ __forceinline__ short f2bf(float f) {
    union { float f; unsigned u; } v; v.f = f;
    unsigned r = v.u + 0x7FFF + ((v.u >> 16) & 1);
    return (short)(r >> 16);
}

// ---------------- convert x (fp32) -> bf16 ----------------
__global__ void convert_x_kernel(const float4* __restrict__ x, short4v* __restrict__ out, int n4) {
    int i = blockIdx.x * blockDim.x + threadIdx.x;
    int stride = gridDim.x * blockDim.x;
    for (; i < n4; i += stride) {
        float4 v = x[i];
        short4v o;
        o[0] = f2bf(v.x); o[1] = f2bf(v.y); o[2] = f2bf(v.z); o[3] = f2bf(v.w);
        out[i] = o;
    }
}

// ---------------- convert Wih_f/Wih_b -> bf16 [1024][1280], combine biases ----------------
__global__ void convert_w_kernel(const float* __restrict__ Wf, const float* __restrict__ Wb,
                                 const float* __restrict__ bihf, const float* __restrict__ bhhf,
                                 const float* __restrict__ bihb, const float* __restrict__ bhhb,
                                 short* __restrict__ wout, float* __restrict__ biasc) {
    int i = blockIdx.x * blockDim.x + threadIdx.x;
    int stride = gridDim.x * blockDim.x;
    const int n4 = (G4 * INDIM) / 4;  // 163840 float4 per direction
    for (int k = i; k < 2 * n4; k += stride) {
        const float4* src = (k < n4) ? (const float4*)Wf : (const float4*)Wb;
        float4 v = src[(k < n4) ? k : (k - n4)];
        short4v o;
        o[0] = f2bf(v.x); o[1] = f2bf(v.y); o[2] = f2bf(v.z); o[3] = f2bf(v.w);
        ((short4v*)wout)[k] = o;
    }
    if (i < NCOLS)
        biasc[i] = (i < G4) ? (bihf[i] + bhhf[i]) : (bihb[i - G4] + bhhb[i - G4]);
}

// ---------------- big GEMM, 256x256 tile, BK=64, 8 waves, counted-vmcnt pipeline ----------------
// xp[32768][1024] = x_bf16[32768][1280] * w_bf16[1024][1280]^T + bias.
// LDS: 2 double-buffers x (A 32KB + B 32KB) = 128KB. Staged via global_load_lds with
// PRE-SWIZZLED global source: LDS 16B-chunk (row, c) holds global chunk c^(row&7)
// (rule #21: linear dest + inverse-swz source + swz on read). Frag reads use
// chunk = (kk*4+lg)^(row&7): verified uniform 2-lane/bank (free).
// Schedule per K-tile: [vmcnt(8); barrier; 64 MFMA from buf; barrier; stage t+2 -> buf]
// -> loads stay in flight across barriers (T4), never drained mid-loop; tail peeled
// with vmcnt(8)/vmcnt(0). 20 K-tiles. Grid: 512 blocks N-fast + bijective XCD swizzle.
#define NT2 20
#define NBLK2 512

__global__ __launch_bounds__(512, 1) void gemm256_kernel(const short* __restrict__ A,
                                                         const short* __restrict__ Bw,
                                                         const float* __restrict__ bias,
                                                         float* __restrict__ C) {
    __shared__ __align__(16) short Ab[2][256 * 64];
    __shared__ __align__(16) short Bb[2][256 * 64];

    // XCD-aware, N-fast decomposition (512 % 8 == 0 -> simple bijection)
    const int orig = blockIdx.x;
    const int logical = (orig & 7) * (NBLK2 / 8) + (orig >> 3);
    const int bn = (logical & 3) * 256;
    const int bm = (logical >> 2) * 256;

    const int tid = threadIdx.x;
    const int w = tid >> 6;          // wave 0..7
    const int l = tid & 63;
    const int lr = l & 15;
    const int lg = l >> 4;           // 0..3
    const int wm2 = (w >> 2) * 128;  // wave M offset (2 waves)
    const int wn2 = (w & 3) * 64;    // wave N offset (4 waves)

    // staging geometry: thread covers chunks {tid, tid+512, tid+1024, tid+1536}
    // chunk id -> (row = id>>3, c = id&7); global col-chunk = c ^ (row&7)
    int arow[4], scol[4];
#pragma unroll
    for (int k = 0; k < 4; k++) {
        const int cid = k * 512 + tid;
        arow[k] = cid >> 3;
        scol[k] = ((cid & 7) ^ (arow[k] & 7)) << 3;  // bf16-elem offset within K-tile
    }
    const short* aptr[4];
    const short* bptr[4];
#pragma unroll
    for (int k = 0; k < 4; k++) {
        aptr[k] = A + (long)(bm + arow[k]) * INDIM + scol[k];
        bptr[k] = Bw + (long)(bn + arow[k]) * INDIM + scol[k];
    }

#define STAGE2(kt, b) { \
    _Pragma("unroll") for (int k_ = 0; k_ < 4; k_++) \
        GLOAD_LDS16(aptr[k_] + (kt) * 64, &Ab[b][(k_ * 512 + w * 64) * 8]); \
    _Pragma("unroll") for (int k_ = 0; k_ < 4; k_++) \
        GLOAD_LDS16(bptr[k_] + (kt) * 64, &Bb[b][(k_ * 512 + w * 64) * 8]); \
}

    f32x4v acc[8][4];
#pragma unroll
    for (int m = 0; m < 8; m++)
#pragma unroll
        for (int n = 0; n < 4; n++) acc[m][n] = (f32x4v)0.0f;

    // swizzled frag-read address (short offset): row*64 + (((kk*4)+lg)^(row&7))*8
#define FRAG_A(b, row, kk) (*(const short8v*)&Ab[b][(row) * 64 + ((((kk) << 2) + lg) ^ ((row) & 7)) * 8])
#define FRAG_B(b, row, kk) (*(const short8v*)&Bb[b][(row) * 64 + ((((kk) << 2) + lg) ^ ((row) & 7)) * 8])

#define COMPUTE2(b) { \
    short8v bfr[4][2]; \
    _Pragma("unroll") for (int nf = 0; nf < 4; nf++) { \
        const int brow = wn2 + nf * 16 + lr; \
        bfr[nf][0] = FRAG_B(b, brow, 0); \
        bfr[nf][1] = FRAG_B(b, brow, 1); \
    } \
    _Pragma("unroll") for (int mf = 0; mf < 8; mf++) { \
        const int amrow = wm2 + mf * 16 + lr; \
        short8v af0 = FRAG_A(b, amrow, 0); \
        short8v af1 = FRAG_A(b, amrow, 1); \
        _Pragma("unroll") for (int nf = 0; nf < 4; nf++) { \
            acc[mf][nf] = __builtin_amdgcn_mfma_f32_16x16x32_bf16(af0, bfr[nf][0], acc[mf][nf], 0, 0, 0); \
            acc[mf][nf] = __builtin_amdgcn_mfma_f32_16x16x32_bf16(af1, bfr[nf][1], acc[mf][nf], 0, 0, 0); \
        } \
    } \
}

    // prologue: stage tiles 0 and 1
    STAGE2(0, 0);
    STAGE2(1, 1);

    for (int t = 0; t < NT2 - 2; ++t) {
        asm volatile("s_waitcnt vmcnt(8)" ::: "memory");  // tile t landed (t+1 in flight)
        __builtin_amdgcn_s_barrier();
        if (t & 1) { COMPUTE2(1); } else { COMPUTE2(0); }
        __builtin_amdgcn_s_barrier();                     // all waves done reading buf
        if (t & 1) { STAGE2(t + 2, 1); } else { STAGE2(t + 2, 0); }
    }
    // t = NT2-2 (18): outstanding {18:8, 19:8}
    asm volatile("s_waitcnt vmcnt(8)" ::: "memory");
    __builtin_amdgcn_s_barrier();
    COMPUTE2(0);
    __builtin_amdgcn_s_barrier();
    // t = NT2-1 (19): outstanding {19:8}
    asm volatile("s_waitcnt vmcnt(0)" ::: "memory");
    __builtin_amdgcn_s_barrier();
    COMPUTE2(1);

    // epilogue: bias + store
#pragma unroll
    for (int nf = 0; nf < 4; nf++) {
        const int col = bn + wn2 + nf * 16 + lr;
        const float bv = bias[col];
#pragma unroll
        for (int mf = 0; mf < 8; mf++) {
            const int row = bm + wm2 + mf * 16 + lg * 4;
#pragma unroll
            for (int r = 0; r < 4; r++)
                C[(long)(row + r) * NCOLS + col] = acc[mf][nf][r] + bv;
        }
    }
#undef STAGE2
#undef COMPUTE2
#undef FRAG_A
#undef FRAG_B
}

// ---------------- recurrence: 64 blocks = 32 batch-groups (2 batches) x 2 directions ----------------
// R5-exact (measured 333us): 256 threads = 4 waves (1/SIMD), wave w = gate w.
// Swapped MFMA gates^T = Whh*h^T; glds[4][2][136] stride-136 conflict-free; h via
// hbf[buf][3][136] with shared zero row; two lgkm-only barriers/step; xp prefetch 2 ahead.
__global__ __launch_bounds__(256, 1) void lstm_rec_kernel(const float* __restrict__ xp,
                                                          const float* __restrict__ Whh_f,
                                                          const float* __restrict__ Whh_b,
                                                          float* __restrict__ pooled) {
    __shared__ __align__(16) short hbf[2][3][136];    // rows 0,1 = batches; row 2 = zeros
    __shared__ __align__(16) float glds[4][2][136];   // [gate i,f,g,o][batch][col]

    const int bid = blockIdx.x;  // 0..63
    const int d = bid & 1;
    const int b0 = (bid >> 1) * 2;   // 2 batches per block
    const int tid = threadIdx.x;
    const int w = tid >> 6;      // wave 0..3 = gate index
    const int l = tid & 63;
    const int lr = l & 15;       // MFMA fragment row / output col (batch)
    const int lg = l >> 4;       // 0..3
    const int lk = lg * 8;
    const int hrow = lr < 2 ? lr : 2;  // broadcast zero row for invalid batches

    const float* __restrict__ Whh = d ? Whh_b : Whh_f;

    short8v afragW[8][4];
#pragma unroll
    for (int nt = 0; nt < 8; nt++) {
        const int gc = w * 128 + nt * 16 + lr;
#pragma unroll
        for (int kk = 0; kk < 4; kk++) {
            const float* src = Whh + gc * HDIM + kk * 32 + lk;
            short8v f;
#pragma unroll
            for (int j = 0; j < 8; j++) f[j] = f2bf(src[j]);
            afragW[nt][kk] = f;
        }
    }

    for (int i = tid; i < 2 * 3 * 136; i += 256) ((short*)hbf)[i] = 0;

    const int eb = tid >> 7;     // batch 0..1
    const int ec = tid & 127;    // hidden col 0..127
    const float* xbase = xp + (long)(b0 + eb) * T_LEN * NCOLS + d * G4 + ec;

    float c = 0.0f;
    float hmax = -1e30f;

#define LOADXV(tq, dst) { \
    int tt_ = d ? (T_LEN - 1 - (tq)) : (tq); \
    tt_ = tt_ < 0 ? 0 : (tt_ > T_LEN - 1 ? T_LEN - 1 : tt_); \
    const float* p_ = xbase + (long)tt_ * NCOLS; \
    _Pragma("unroll") for (int nt_ = 0; nt_ < 4; nt_++) \
        dst[nt_] = p_[nt_ * 128]; \
}

    float xvA[4], xvB[4];
    LOADXV(0, xvA);
    LOADXV(1, xvB);

    __syncthreads();

#define L2E 1.44269504088896f

#define STEP(t, pb, xv) { \
    short8v hfrag[4]; \
    _Pragma("unroll") for (int kk = 0; kk < 4; kk++) \
        hfrag[kk] = *(const short8v*)&hbf[pb][hrow][kk * 32 + lk]; \
    _Pragma("unroll") for (int nt = 0; nt < 8; nt++) { \
        f32x4v a = (f32x4v)0.0f; \
        _Pragma("unroll") for (int kk = 0; kk < 4; kk++) \
            a = __builtin_amdgcn_mfma_f32_16x16x32_bf16(afragW[nt][kk], hfrag[kk], a, 0, 0, 0); \
        if (lr < 2) *(f32x4v*)&glds[w][lr][nt * 16 + lg * 4] = a; \
    } \
    asm volatile("s_waitcnt lgkmcnt(0)\n\ts_barrier" ::: "memory"); \
    { \
        float gi = glds[0][eb][ec] + xv[0]; \
        float gf = glds[1][eb][ec] + xv[1]; \
        float gg = glds[2][eb][ec] + xv[2]; \
        float go = glds[3][eb][ec] + xv[3]; \
        float ea = __builtin_amdgcn_exp2f(-gi * L2E); \
        float eb_ = __builtin_amdgcn_exp2f(-gf * L2E); \
        float pa = 1.0f + ea, pbv = 1.0f + eb_; \
        float inv1 = __builtin_amdgcn_rcpf(pa * pbv); \
        float si = pbv * inv1; \
        float sf = pa * inv1; \
        float eg = __builtin_amdgcn_exp2f(gg * (2.0f * L2E)); \
        float eo = __builtin_amdgcn_exp2f(-go * L2E); \
        float pg = 1.0f + eg, po = 1.0f + eo; \
        float inv2 = __builtin_amdgcn_rcpf(pg * po); \
        float tg = 1.0f - 2.0f * po * inv2; \
        float so = pg * inv2; \
        c = sf * c + si * tg; \
        float ecx = __builtin_amdgcn_exp2f(c * (2.0f * L2E)); \
        float tc = 1.0f - 2.0f * __builtin_amdgcn_rcpf(1.0f + ecx); \
        float h = so * tc; \
        hmax = fmaxf(hmax, h); \
        hbf[(pb) ^ 1][eb][ec] = f2bf(h); \
    } \
    LOADXV((t) + 2, xv); \
    asm volatile("s_waitcnt lgkmcnt(0)\n\ts_barrier" ::: "memory"); \
}

    for (int t = 0; t < T_LEN; t += 2) {
        STEP(t, 0, xvA);
        STEP(t + 1, 1, xvB);
    }

    pooled[(b0 + eb) * 256 + d * 128 + ec] = hmax;
#undef STEP
#undef LOADXV
}

// ---------------- head: out[64][263] = pooled[64][256] @ W1^T + b1 ----------------
__global__ void logits_kernel(const float* __restrict__ pooled, const float* __restrict__ W1,
                              const float* __restrict__ b1, float* __restrict__ out) {
    __shared__ float p[256];
    const int b = blockIdx.x;
    const int n = threadIdx.x;
    if (n < 256) p[n] = pooled[b * 256 + n];
    __syncthreads();
    if (n < NCLS) {
        float s = b1[n];
        const float* wr = W1 + n * 256;
#pragma unroll 8
        for (int k = 0; k < 256; k++) s += p[k] * wr[k];
        out[b * NCLS + n] = s;
    }
}

extern "C" void kernel_launch(void* const* d_in, const int* in_sizes, int n_in,
                              void* d_out, int out_size, void* d_ws, size_t ws_size,
                              hipStream_t stream) {
    (void)in_sizes; (void)n_in; (void)out_size; (void)ws_size;
    const float* x     = (const float*)d_in[0];
    const float* Wih_f = (const float*)d_in[1];
    const float* Whh_f = (const float*)d_in[2];
    const float* bih_f = (const float*)d_in[3];
    const float* bhh_f = (const float*)d_in[4];
    const float* Wih_b = (const float*)d_in[5];
    const float* Whh_b = (const float*)d_in[6];
    const float* bih_b = (const float*)d_in[7];
    const float* bhh_b = (const float*)d_in[8];
    const float* W1    = (const float*)d_in[9];
    const float* b1    = (const float*)d_in[10];
    float* out = (float*)d_out;

    char* ws = (char*)d_ws;
    short* x_bf   = (short*)ws;                    // 32768*1280*2  = 83,886,080
    short* w_bf   = (short*)(ws + 83886080);       // 1024*1280*2   =  2,621,440
    float* biasc  = (float*)(ws + 86507520);       // 1024*4        =      4,096
    float* xp     = (float*)(ws + 86511616);       // 32768*1024*4  = 134,217,728
    float* pooled = (float*)(ws + 220729344);      // 64*256*4      =     65,536

    convert_x_kernel<<<2048, 256, 0, stream>>>((const float4*)x, (short4v*)x_bf, (T_LEN * BATCH * INDIM) / 4);
    convert_w_kernel<<<512, 256, 0, stream>>>(Wih_f, Wih_b, bih_f, bhh_f, bih_b, bhh_b, w_bf, biasc);
    gemm256_kernel<<<NBLK2, 512, 0, stream>>>(x_bf, w_bf, biasc, xp);
    lstm_rec_kernel<<<64, 256, 0, stream>>>(xp, Whh_f, Whh_b, pooled);
    logits_kernel<<<64, 320, 0, stream>>>(pooled, W1, b1, out);
}

// Round 13
// 508.413 us; speedup vs baseline: 1.3298x; 1.3298x over previous
//
#include <hip/hip_runtime.h>
#include <hip/hip_bf16.h>

typedef short short8v __attribute__((ext_vector_type(8)));
typedef short short4v __attribute__((ext_vector_type(4)));
typedef float f32x4v __attribute__((ext_vector_type(4)));

#define T_LEN 512
#define BATCH 64
#define INDIM 1280
#define HDIM 128
#define G4 512      // 4*H (one direction)
#define NCOLS 1024  // both directions
#define NCLS 263

typedef __attribute__((address_space(1))) const void gvoid_t;
typedef __attribute__((address_space(3))) void lvoid_t;
#define GLOAD_LDS16(g, l) __builtin_amdgcn_global_load_lds((gvoid_t*)(g), (lvoid_t*)(l), 16, 0, 0)

static __device__ __forceinline__ short f2bf(float f) {
    union { float f; unsigned u; } v; v.f = f;
    unsigned r = v.u + 0x7FFF + ((v.u >> 16) & 1);
    return (short)(r >> 16);
}

// ---------------- convert x (fp32) -> bf16 ----------------
__global__ void convert_x_kernel(const float4* __restrict__ x, short4v* __restrict__ out, int n4) {
    int i = blockIdx.x * blockDim.x + threadIdx.x;
    int stride = gridDim.x * blockDim.x;
    for (; i < n4; i += stride) {
        float4 v = x[i];
        short4v o;
        o[0] = f2bf(v.x); o[1] = f2bf(v.y); o[2] = f2bf(v.z); o[3] = f2bf(v.w);
        out[i] = o;
    }
}

// ---------------- convert Wih_f/Wih_b -> bf16 [1024][1280], combine biases ----------------
__global__ void convert_w_kernel(const float* __restrict__ Wf, const float* __restrict__ Wb,
                                 const float* __restrict__ bihf, const float* __restrict__ bhhf,
                                 const float* __restrict__ bihb, const float* __restrict__ bhhb,
                                 short* __restrict__ wout, float* __restrict__ biasc) {
    int i = blockIdx.x * blockDim.x + threadIdx.x;
    int stride = gridDim.x * blockDim.x;
    const int n4 = (G4 * INDIM) / 4;  // 163840 float4 per direction
    for (int k = i; k < 2 * n4; k += stride) {
        const float4* src = (k < n4) ? (const float4*)Wf : (const float4*)Wb;
        float4 v = src[(k < n4) ? k : (k - n4)];
        short4v o;
        o[0] = f2bf(v.x); o[1] = f2bf(v.y); o[2] = f2bf(v.z); o[3] = f2bf(v.w);
        ((short4v*)wout)[k] = o;
    }
    if (i < NCOLS)
        biasc[i] = (i < G4) ? (bihf[i] + bhhf[i]) : (bihb[i - G4] + bhhb[i - G4]);
}

// ---------------- big GEMM: xp[32768][1024] = x_bf16 * w_bf16^T + bias ----------------
// 128x128 tile, BK=64 (20 iters, half the barrier drains of BK=32), 4 waves.
// Grid: 2048 blocks, XCD-chunked bijective swizzle with N-FAST logical order:
// each XCD owns 32 M-slabs x all 8 N-tiles -> A-slab (320KB) is fetched into ONE
// XCD's L2 once and re-read 8x from L2, instead of 8x from L3/HBM (old M-fast grid).
#define BM 128
#define BN 128
#define BK 64
#define GBLK 2048

__global__ __launch_bounds__(256) void gemm_xp_kernel(const short* __restrict__ A,
                                                      const short* __restrict__ Bw,
                                                      const float* __restrict__ bias,
                                                      float* __restrict__ C) {
    __shared__ __align__(16) short As[BM * BK];
    __shared__ __align__(16) short Bs[BN * BK];
    const int tid = threadIdx.x;
    const int w = tid >> 6;
    const int l = tid & 63;

    // XCD-chunked bijective swizzle (2048 % 8 == 0), N-fast logical order
    const int orig = blockIdx.x;
    const int logical = (orig & 7) * (GBLK / 8) + (orig >> 3);
    const int bn = (logical & 7) * BN;
    const int bm = (logical >> 3) * BM;

    const int wm = (w >> 1) * 64;
    const int wn = (w & 1) * 64;
    const int lr = l & 15;
    const int lk = (l >> 4) * 8;

    f32x4v acc[4][4];
#pragma unroll
    for (int m = 0; m < 4; m++)
#pragma unroll
        for (int n = 0; n < 4; n++) acc[m][n] = (f32x4v)0.0f;

    // staging geometry: 128 rows x 8 chunks (16B) = 1024 chunks; thread covers
    // chunks {c*256 + tid}, c=0..3. row = chunk>>3, colchunk = chunk&7.
    const short* aptr[4];
    const short* bptr[4];
#pragma unroll
    for (int c = 0; c < 4; c++) {
        const int chunk = c * 256 + tid;
        const int row = chunk >> 3;
        const int col = (chunk & 7) * 8;
        aptr[c] = A + (long)(bm + row) * INDIM + col;
        bptr[c] = Bw + (long)(bn + row) * INDIM + col;
    }

#define STAGEK(k0) { \
    _Pragma("unroll") for (int c_ = 0; c_ < 4; c_++) \
        GLOAD_LDS16(aptr[c_] + (k0), &As[(c_ * 256 + w * 64) * 8]); \
    _Pragma("unroll") for (int c_ = 0; c_ < 4; c_++) \
        GLOAD_LDS16(bptr[c_] + (k0), &Bs[(c_ * 256 + w * 64) * 8]); \
}

    // prologue: stage k0=0
    STAGEK(0);

    for (int k0 = 0; k0 < INDIM; k0 += BK) {
        __syncthreads();  // staged data visible
        short8v af[4][2], bf[4][2];
#pragma unroll
        for (int m = 0; m < 4; m++)
#pragma unroll
            for (int ks = 0; ks < 2; ks++)
                af[m][ks] = *(const short8v*)&As[(wm + m * 16 + lr) * BK + ks * 32 + lk];
#pragma unroll
        for (int n = 0; n < 4; n++)
#pragma unroll
            for (int ks = 0; ks < 2; ks++)
                bf[n][ks] = *(const short8v*)&Bs[(wn + n * 16 + lr) * BK + ks * 32 + lk];
        __syncthreads();  // all waves done reading LDS
        if (k0 + BK < INDIM) STAGEK(k0 + BK);
#pragma unroll
        for (int ks = 0; ks < 2; ks++)
#pragma unroll
            for (int m = 0; m < 4; m++)
#pragma unroll
                for (int n = 0; n < 4; n++)
                    acc[m][n] = __builtin_amdgcn_mfma_f32_16x16x32_bf16(af[m][ks], bf[n][ks], acc[m][n], 0, 0, 0);
    }

    // epilogue: add bias, store fp32
#pragma unroll
    for (int m = 0; m < 4; m++) {
        const int row = bm + wm + m * 16 + (l >> 4) * 4;
#pragma unroll
        for (int n = 0; n < 4; n++) {
            const int col = bn + wn + n * 16 + lr;
            const float bv = bias[col];
#pragma unroll
            for (int r = 0; r < 4; r++)
                C[(long)(row + r) * NCOLS + col] = acc[m][n][r] + bv;
        }
    }
#undef STAGEK
}

// ---------------- recurrence: 64 blocks = 32 batch-groups (2 batches) x 2 directions ----------------
// R5-exact (measured 333us): 256 threads = 4 waves (1/SIMD), wave w = gate w.
// Swapped MFMA gates^T = Whh*h^T; glds[4][2][136] stride-136 conflict-free; h via
// hbf[buf][3][136] with shared zero row; two lgkm-only barriers/step; xp prefetch 2 ahead.
__global__ __launch_bounds__(256, 1) void lstm_rec_kernel(const float* __restrict__ xp,
                                                          const float* __restrict__ Whh_f,
                                                          const float* __restrict__ Whh_b,
                                                          float* __restrict__ pooled) {
    __shared__ __align__(16) short hbf[2][3][136];    // rows 0,1 = batches; row 2 = zeros
    __shared__ __align__(16) float glds[4][2][136];   // [gate i,f,g,o][batch][col]

    const int bid = blockIdx.x;  // 0..63
    const int d = bid & 1;
    const int b0 = (bid >> 1) * 2;   // 2 batches per block
    const int tid = threadIdx.x;
    const int w = tid >> 6;      // wave 0..3 = gate index
    const int l = tid & 63;
    const int lr = l & 15;       // MFMA fragment row / output col (batch)
    const int lg = l >> 4;       // 0..3
    const int lk = lg * 8;
    const int hrow = lr < 2 ? lr : 2;  // broadcast zero row for invalid batches

    const float* __restrict__ Whh = d ? Whh_b : Whh_f;

    short8v afragW[8][4];
#pragma unroll
    for (int nt = 0; nt < 8; nt++) {
        const int gc = w * 128 + nt * 16 + lr;
#pragma unroll
        for (int kk = 0; kk < 4; kk++) {
            const float* src = Whh + gc * HDIM + kk * 32 + lk;
            short8v f;
#pragma unroll
            for (int j = 0; j < 8; j++) f[j] = f2bf(src[j]);
            afragW[nt][kk] = f;
        }
    }

    for (int i = tid; i < 2 * 3 * 136; i += 256) ((short*)hbf)[i] = 0;

    const int eb = tid >> 7;     // batch 0..1
    const int ec = tid & 127;    // hidden col 0..127
    const float* xbase = xp + (long)(b0 + eb) * T_LEN * NCOLS + d * G4 + ec;

    float c = 0.0f;
    float hmax = -1e30f;

#define LOADXV(tq, dst) { \
    int tt_ = d ? (T_LEN - 1 - (tq)) : (tq); \
    tt_ = tt_ < 0 ? 0 : (tt_ > T_LEN - 1 ? T_LEN - 1 : tt_); \
    const float* p_ = xbase + (long)tt_ * NCOLS; \
    _Pragma("unroll") for (int nt_ = 0; nt_ < 4; nt_++) \
        dst[nt_] = p_[nt_ * 128]; \
}

    float xvA[4], xvB[4];
    LOADXV(0, xvA);
    LOADXV(1, xvB);

    __syncthreads();

#define L2E 1.44269504088896f

#define STEP(t, pb, xv) { \
    short8v hfrag[4]; \
    _Pragma("unroll") for (int kk = 0; kk < 4; kk++) \
        hfrag[kk] = *(const short8v*)&hbf[pb][hrow][kk * 32 + lk]; \
    _Pragma("unroll") for (int nt = 0; nt < 8; nt++) { \
        f32x4v a = (f32x4v)0.0f; \
        _Pragma("unroll") for (int kk = 0; kk < 4; kk++) \
            a = __builtin_amdgcn_mfma_f32_16x16x32_bf16(afragW[nt][kk], hfrag[kk], a, 0, 0, 0); \
        if (lr < 2) *(f32x4v*)&glds[w][lr][nt * 16 + lg * 4] = a; \
    } \
    asm volatile("s_waitcnt lgkmcnt(0)\n\ts_barrier" ::: "memory"); \
    { \
        float gi = glds[0][eb][ec] + xv[0]; \
        float gf = glds[1][eb][ec] + xv[1]; \
        float gg = glds[2][eb][ec] + xv[2]; \
        float go = glds[3][eb][ec] + xv[3]; \
        float ea = __builtin_amdgcn_exp2f(-gi * L2E); \
        float eb_ = __builtin_amdgcn_exp2f(-gf * L2E); \
        float pa = 1.0f + ea, pbv = 1.0f + eb_; \
        float inv1 = __builtin_amdgcn_rcpf(pa * pbv); \
        float si = pbv * inv1; \
        float sf = pa * inv1; \
        float eg = __builtin_amdgcn_exp2f(gg * (2.0f * L2E)); \
        float eo = __builtin_amdgcn_exp2f(-go * L2E); \
        float pg = 1.0f + eg, po = 1.0f + eo; \
        float inv2 = __builtin_amdgcn_rcpf(pg * po); \
        float tg = 1.0f - 2.0f * po * inv2; \
        float so = pg * inv2; \
        c = sf * c + si * tg; \
        float ecx = __builtin_amdgcn_exp2f(c * (2.0f * L2E)); \
        float tc = 1.0f - 2.0f * __builtin_amdgcn_rcpf(1.0f + ecx); \
        float h = so * tc; \
        hmax = fmaxf(hmax, h); \
        hbf[(pb) ^ 1][eb][ec] = f2bf(h); \
    } \
    LOADXV((t) + 2, xv); \
    asm volatile("s_waitcnt lgkmcnt(0)\n\ts_barrier" ::: "memory"); \
}

    for (int t = 0; t < T_LEN; t += 2) {
        STEP(t, 0, xvA);
        STEP(t + 1, 1, xvB);
    }

    pooled[(b0 + eb) * 256 + d * 128 + ec] = hmax;
#undef STEP
#undef LOADXV
}

// ---------------- head: out[64][263] = pooled[64][256] @ W1^T + b1 ----------------
__global__ void logits_kernel(const float* __restrict__ pooled, const float* __restrict__ W1,
                              const float* __restrict__ b1, float* __restrict__ out) {
    __shared__ float p[256];
    const int b = blockIdx.x;
    const int n = threadIdx.x;
    if (n < 256) p[n] = pooled[b * 256 + n];
    __syncthreads();
    if (n < NCLS) {
        float s = b1[n];
        const float* wr = W1 + n * 256;
#pragma unroll 8
        for (int k = 0; k < 256; k++) s += p[k] * wr[k];
        out[b * NCLS + n] = s;
    }
}

extern "C" void kernel_launch(void* const* d_in, const int* in_sizes, int n_in,
                              void* d_out, int out_size, void* d_ws, size_t ws_size,
                              hipStream_t stream) {
    (void)in_sizes; (void)n_in; (void)out_size; (void)ws_size;
    const float* x     = (const float*)d_in[0];
    const float* Wih_f = (const float*)d_in[1];
    const float* Whh_f = (const float*)d_in[2];
    const float* bih_f = (const float*)d_in[3];
    const float* bhh_f = (const float*)d_in[4];
    const float* Wih_b = (const float*)d_in[5];
    const float* Whh_b = (const float*)d_in[6];
    const float* bih_b = (const float*)d_in[7];
    const float* bhh_b = (const float*)d_in[8];
    const float* W1    = (const float*)d_in[9];
    const float* b1    = (const float*)d_in[10];
    float* out = (float*)d_out;

    char* ws = (char*)d_ws;
    short* x_bf   = (short*)ws;                    // 32768*1280*2  = 83,886,080
    short* w_bf   = (short*)(ws + 83886080);       // 1024*1280*2   =  2,621,440
    float* biasc  = (float*)(ws + 86507520);       // 1024*4        =      4,096
    float* xp     = (float*)(ws + 86511616);       // 32768*1024*4  = 134,217,728
    float* pooled = (float*)(ws + 220729344);      // 64*256*4      =     65,536

    convert_x_kernel<<<2048, 256, 0, stream>>>((const float4*)x, (short4v*)x_bf, (T_LEN * BATCH * INDIM) / 4);
    convert_w_kernel<<<512, 256, 0, stream>>>(Wih_f, Wih_b, bih_f, bhh_f, bih_b, bhh_b, w_bf, biasc);
    gemm_xp_kernel<<<GBLK, 256, 0, stream>>>(x_bf, w_bf, biasc, xp);
    lstm_rec_kernel<<<64, 256, 0, stream>>>(xp, Whh_f, Whh_b, pooled);
    logits_kernel<<<64, 320, 0, stream>>>(pooled, W1, b1, out);
}